// Round 5
// baseline (242.954 us; speedup 1.0000x reference)
//
#include <hip/hip_runtime.h>
#include <hip/hip_fp16.h>

// QuantizedLinearWhisper: E2M1 block-32 fake-quant of x and W, then x_q @ W_q^T + bias.
// M=12000 (pad 12032=47*256), K=1280, N=5120. Outputs: out[12000][5120] f32, scale_w[5120][40] f32.
//
// R5: 256x256 GEMM, software-pipelined fragment reads (1 phase ahead, ping-pong sets
// via template parity), only 2 barriers/tile (staging-safety + post-vmcnt), counted
// vmcnt(8), setprio around MFMA clusters, 3-bit XOR swizzle (0 conflicts, proven).
// Goal: overlap LDS-read bursts with MFMA clusters instead of serializing per phase.

typedef _Float16 f16;
typedef _Float16 f16x8 __attribute__((ext_vector_type(8)));
typedef float f32x4 __attribute__((ext_vector_type(4)));

#define M_ROWS 12000
#define M_PAD  12032
#define N_COLS 5120
#define K_DIM  1280
#define KB     40
#define NT     20          // K tiles of 64
#define NTN    20          // N tiles of 256

#define BAR()   asm volatile("s_barrier" ::: "memory")
#define LGKM0() asm volatile("s_waitcnt lgkmcnt(0)" ::: "memory")
#define GLDS(gp, lp) __builtin_amdgcn_global_load_lds( \
    (const __attribute__((address_space(1))) unsigned*)(gp), \
    (__attribute__((address_space(3))) unsigned*)(lp), 16, 0, 0)

// ---- E2M1 nearest-level (strict > boundaries, identical to reference) ----
__device__ __forceinline__ float e2m1_level(float a) {
    float lv;
    if (a > 2.5f)       lv = (a > 3.5f) ? ((a > 5.0f) ? 6.0f : 4.0f) : 3.0f;
    else if (a > 1.25f) lv = (a > 1.75f) ? 2.0f : 1.5f;
    else                lv = (a > 0.75f) ? 1.0f : ((a > 0.25f) ? 0.5f : 0.0f);
    return lv;
}

__global__ __launch_bounds__(256) void quant_x_kernel(const float* __restrict__ x,
                                                      f16* __restrict__ xq) {
    int t = blockIdx.x * blockDim.x + threadIdx.x;
    int row = t / 160;
    int c8  = t % 160;
    f16x8 o;
    if (row < M_ROWS) {
        const float* p = x + (size_t)row * K_DIM + c8 * 8;
        float v[8];
        *(float4*)&v[0] = *(const float4*)p;
        *(float4*)&v[4] = *(const float4*)(p + 4);
        float am = 0.0f;
        #pragma unroll
        for (int i = 0; i < 8; ++i) am = fmaxf(am, fabsf(v[i]));
        am = fmaxf(am, __shfl_xor(am, 1));
        am = fmaxf(am, __shfl_xor(am, 2));
        float scale = fmaxf(am / 6.0f, 1e-12f);
        #pragma unroll
        for (int i = 0; i < 8; ++i) {
            float tq = v[i] / scale;
            float q  = copysignf(e2m1_level(fabsf(tq)), tq) * scale;
            o[i] = (f16)q;
        }
    } else {
        #pragma unroll
        for (int i = 0; i < 8; ++i) o[i] = (f16)0.0f;
    }
    *(f16x8*)(xq + (size_t)row * K_DIM + c8 * 8) = o;
}

__global__ __launch_bounds__(256) void quant_w_kernel(const float* __restrict__ w,
                                                      f16* __restrict__ wq,
                                                      float* __restrict__ scale_out) {
    int t = blockIdx.x * blockDim.x + threadIdx.x;
    int row = t / 160;
    int c8  = t % 160;
    const float* p = w + (size_t)row * K_DIM + c8 * 8;
    float v[8];
    *(float4*)&v[0] = *(const float4*)p;
    *(float4*)&v[4] = *(const float4*)(p + 4);
    float am = 0.0f;
    #pragma unroll
    for (int i = 0; i < 8; ++i) am = fmaxf(am, fabsf(v[i]));
    am = fmaxf(am, __shfl_xor(am, 1));
    am = fmaxf(am, __shfl_xor(am, 2));
    float scale = fmaxf(am / 6.0f, 1e-12f);
    if ((t & 3) == 0) scale_out[row * KB + (c8 >> 2)] = scale;
    f16x8 o;
    #pragma unroll
    for (int i = 0; i < 8; ++i) {
        float tq = v[i] / scale;
        float q  = copysignf(e2m1_level(fabsf(tq)), tq) * scale;
        o[i] = (f16)q;
    }
    *(f16x8*)(wq + (size_t)row * K_DIM + c8 * 8) = o;
}

// ---- GEMM 256x256, BK=64, 512 threads (8 waves 2x4), per-wave 128x64 out ----
// LDS per buffer: A [256 rows][8 chunks of 16B] (32KB) + B same; chunk c of row r
// stored at slot (c ^ (r&7)); stage pre-swizzles the global source chunk.

__device__ __forceinline__ void stage_half(const f16* __restrict__ g, f16* l, int tid) {
    #pragma unroll
    for (int s = 0; s < 2; ++s) {
        int j = s * 512 + tid;          // chunk 0..1023
        int r = j >> 3;
        int c = (j & 7) ^ (r & 7);
        GLDS(g + (size_t)r * K_DIM + c * 8, l + (size_t)j * 8);
    }
}

// One K-tile. PAR = frag-set parity for this tile (== buffer parity).
// a0/b0 hold this tile's first-quadrant frags (read at previous tile's S3);
// S3 reads next tile's a0/b0 into set 1-PAR from the next buffer.
// Schedule: S0{read b1; Q1} S1{read a1; Q2} S2{[lgkm0+bar+stage X<-t+2]; Q3}
//           S3{[vmcnt+bar+read next a0,b0]; Q4}
template<int PAR, bool STAGE, int VM, bool READNEXT>
__device__ __forceinline__ void tile_body(f16* Xa, f16* Xb,
                                          const f16* Na, const f16* Nb,
                                          const f16* gA2, const f16* gB2,
                                          f16x8 (&a0)[2][4][2], f16x8 (&b0)[2][2][2],
                                          f32x4 (&acc)[8][4],
                                          int tid, int arow0, int brow0,
                                          const int (&swz)[2]) {
    f16x8 b1[2][2], a1[4][2];

    // ---- S0: read b1 (4); MFMA Q1 = a0·b0 -> acc[0-3][0-1]
    #pragma unroll
    for (int fn = 0; fn < 2; ++fn) {
        b1[fn][0] = *(const f16x8*)&Xb[(brow0 + 32 + fn * 16) * 64 + swz[0]];
        b1[fn][1] = *(const f16x8*)&Xb[(brow0 + 32 + fn * 16) * 64 + swz[1]];
    }
    __builtin_amdgcn_s_setprio(1);
    #pragma unroll
    for (int fm = 0; fm < 4; ++fm)
        #pragma unroll
        for (int fn = 0; fn < 2; ++fn) {
            acc[fm][fn] = __builtin_amdgcn_mfma_f32_16x16x32_f16(a0[PAR][fm][0], b0[PAR][fn][0], acc[fm][fn], 0, 0, 0);
            acc[fm][fn] = __builtin_amdgcn_mfma_f32_16x16x32_f16(a0[PAR][fm][1], b0[PAR][fn][1], acc[fm][fn], 0, 0, 0);
        }
    __builtin_amdgcn_s_setprio(0);

    // ---- S1: read a1 (8); MFMA Q2 = a0·b1 -> acc[0-3][2-3]
    #pragma unroll
    for (int fm = 0; fm < 4; ++fm) {
        a1[fm][0] = *(const f16x8*)&Xa[(arow0 + 64 + fm * 16) * 64 + swz[0]];
        a1[fm][1] = *(const f16x8*)&Xa[(arow0 + 64 + fm * 16) * 64 + swz[1]];
    }
    __builtin_amdgcn_s_setprio(1);
    #pragma unroll
    for (int fm = 0; fm < 4; ++fm)
        #pragma unroll
        for (int fn = 0; fn < 2; ++fn) {
            acc[fm][fn + 2] = __builtin_amdgcn_mfma_f32_16x16x32_f16(a0[PAR][fm][0], b1[fn][0], acc[fm][fn + 2], 0, 0, 0);
            acc[fm][fn + 2] = __builtin_amdgcn_mfma_f32_16x16x32_f16(a0[PAR][fm][1], b1[fn][1], acc[fm][fn + 2], 0, 0, 0);
        }
    __builtin_amdgcn_s_setprio(0);

    // ---- S2: re-stage this buffer with tile t+2 (all reads of it are drained first);
    //          MFMA Q3 = a1·b1 -> acc[4-7][2-3]
    if (STAGE) {
        LGKM0();                  // my ds_reads of X (incl. prev-S3 a0/b0 reads) done
        BAR();                    // everyone's done -> safe to overwrite X
        stage_half(gA2,               Xa,        tid);
        stage_half(gA2 + 128 * K_DIM, Xa + 8192, tid);
        stage_half(gB2,               Xb,        tid);
        stage_half(gB2 + 128 * K_DIM, Xb + 8192, tid);
    }
    __builtin_amdgcn_s_setprio(1);
    #pragma unroll
    for (int fm = 0; fm < 4; ++fm)
        #pragma unroll
        for (int fn = 0; fn < 2; ++fn) {
            acc[fm + 4][fn + 2] = __builtin_amdgcn_mfma_f32_16x16x32_f16(a1[fm][0], b1[fn][0], acc[fm + 4][fn + 2], 0, 0, 0);
            acc[fm + 4][fn + 2] = __builtin_amdgcn_mfma_f32_16x16x32_f16(a1[fm][1], b1[fn][1], acc[fm + 4][fn + 2], 0, 0, 0);
        }
    __builtin_amdgcn_s_setprio(0);

    // ---- S3: next buffer is fully staged after counted vmcnt + barrier; read next
    //          tile's a0/b0 into set 1-PAR; MFMA Q4 = a1·b0[PAR] -> acc[4-7][0-1]
    if (READNEXT) {
        if (VM == 8)  asm volatile("s_waitcnt vmcnt(8)" ::: "memory");
        else          asm volatile("s_waitcnt vmcnt(0)" ::: "memory");
        BAR();                    // everyone's staging loads for next buffer retired
        #pragma unroll
        for (int fm = 0; fm < 4; ++fm) {
            a0[1 - PAR][fm][0] = *(const f16x8*)&Na[(arow0 + fm * 16) * 64 + swz[0]];
            a0[1 - PAR][fm][1] = *(const f16x8*)&Na[(arow0 + fm * 16) * 64 + swz[1]];
        }
        #pragma unroll
        for (int fn = 0; fn < 2; ++fn) {
            b0[1 - PAR][fn][0] = *(const f16x8*)&Nb[(brow0 + fn * 16) * 64 + swz[0]];
            b0[1 - PAR][fn][1] = *(const f16x8*)&Nb[(brow0 + fn * 16) * 64 + swz[1]];
        }
    }
    __builtin_amdgcn_s_setprio(1);
    #pragma unroll
    for (int fm = 0; fm < 4; ++fm)
        #pragma unroll
        for (int fn = 0; fn < 2; ++fn) {
            acc[fm + 4][fn] = __builtin_amdgcn_mfma_f32_16x16x32_f16(a1[fm][0], b0[PAR][fn][0], acc[fm + 4][fn], 0, 0, 0);
            acc[fm + 4][fn] = __builtin_amdgcn_mfma_f32_16x16x32_f16(a1[fm][1], b0[PAR][fn][1], acc[fm + 4][fn], 0, 0, 0);
        }
    __builtin_amdgcn_s_setprio(0);
}

__global__ __launch_bounds__(512, 2) void gemm_kernel(const f16* __restrict__ A,
                                                      const f16* __restrict__ B,
                                                      const float* __restrict__ bias,
                                                      float* __restrict__ C) {
    extern __shared__ f16 sm[];            // 2 bufs x (A 16384 + B 16384 f16) = 128 KiB
    int mt = blockIdx.x / NTN;
    int nt = blockIdx.x % NTN;

    int tid  = threadIdx.x;
    int lane = tid & 63;
    int wid  = tid >> 6;
    int wr   = wid >> 2;                   // 0..1
    int wc   = wid & 3;                    // 0..3
    int l15  = lane & 15;

    int swz[2] = { (((lane >> 4)    ) ^ (lane & 7)) * 8,
                   (((lane >> 4) + 4) ^ (lane & 7)) * 8 };
    int arow0 = wr * 128 + l15;
    int brow0 = wc * 64 + l15;

    const f16* gAb = A + (size_t)(mt * 256) * K_DIM;
    const f16* gBb = B + (size_t)(nt * 256) * K_DIM;

    f16* A0 = sm;
    f16* B0 = sm + 16384;
    f16* A1 = sm + 32768;
    f16* B1 = sm + 49152;

    f32x4 acc[8][4] = {};
    f16x8 a0[2][4][2];
    f16x8 b0[2][2][2];

    // prologue: stage tile 0 -> buf0, tile 1 -> buf1; retire tile 0 (8 newest remain);
    // read tile-0 first-quadrant frags (set 0)
    stage_half(gAb,               A0,        tid);
    stage_half(gAb + 128 * K_DIM, A0 + 8192, tid);
    stage_half(gBb,               B0,        tid);
    stage_half(gBb + 128 * K_DIM, B0 + 8192, tid);
    stage_half(gAb + 64,               A1,        tid);
    stage_half(gAb + 64 + 128 * K_DIM, A1 + 8192, tid);
    stage_half(gBb + 64,               B1,        tid);
    stage_half(gBb + 64 + 128 * K_DIM, B1 + 8192, tid);
    asm volatile("s_waitcnt vmcnt(8)" ::: "memory");
    BAR();
    #pragma unroll
    for (int fm = 0; fm < 4; ++fm) {
        a0[0][fm][0] = *(const f16x8*)&A0[(arow0 + fm * 16) * 64 + swz[0]];
        a0[0][fm][1] = *(const f16x8*)&A0[(arow0 + fm * 16) * 64 + swz[1]];
    }
    #pragma unroll
    for (int fn = 0; fn < 2; ++fn) {
        b0[0][fn][0] = *(const f16x8*)&B0[(brow0 + fn * 16) * 64 + swz[0]];
        b0[0][fn][1] = *(const f16x8*)&B0[(brow0 + fn * 16) * 64 + swz[1]];
    }

    // main loop: tiles 0..17 (staged pairs), then 18 (vmcnt 0), 19 (no read-next)
    for (int tt = 0; tt < 9; ++tt) {
        int t0 = 2 * tt;
        tile_body<0, true, 8, true>(A0, B0, A1, B1,
                                    gAb + (t0 + 2) * 64, gBb + (t0 + 2) * 64,
                                    a0, b0, acc, tid, arow0, brow0, swz);
        tile_body<1, true, 8, true>(A1, B1, A0, B0,
                                    gAb + (t0 + 3) * 64, gBb + (t0 + 3) * 64,
                                    a0, b0, acc, tid, arow0, brow0, swz);
    }
    tile_body<0, false, 0, true>(A0, B0, A1, B1, gAb, gBb,
                                 a0, b0, acc, tid, arow0, brow0, swz);   // t=18
    tile_body<1, false, -1, false>(A1, B1, A0, B0, gAb, gBb,
                                   a0, b0, acc, tid, arow0, brow0, swz); // t=19

    // ---- epilogue: C = acc + bias.  C/D layout: col=lane&15, row=(lane>>4)*4+j
    int crow0 = mt * 256 + wr * 128;
    int ccol  = nt * 256 + wc * 64 + l15;
    float bz[4];
    #pragma unroll
    for (int fn = 0; fn < 4; ++fn) bz[fn] = bias[ccol + fn * 16];

    #pragma unroll
    for (int fm = 0; fm < 8; ++fm) {
        #pragma unroll
        for (int j = 0; j < 4; ++j) {
            int row = crow0 + fm * 16 + (lane >> 4) * 4 + j;
            if (row < M_ROWS) {
                float* cp = C + (size_t)row * N_COLS + ccol;
                #pragma unroll
                for (int fn = 0; fn < 4; ++fn)
                    cp[fn * 16] = acc[fm][fn][j] + bz[fn];
            }
        }
    }
}

extern "C" void kernel_launch(void* const* d_in, const int* in_sizes, int n_in,
                              void* d_out, int out_size, void* d_ws, size_t ws_size,
                              hipStream_t stream) {
    const float* x      = (const float*)d_in[0];
    const float* weight = (const float*)d_in[1];
    const float* bias   = (const float*)d_in[2];
    float* out     = (float*)d_out;
    float* scale_w = (float*)d_out + (size_t)M_ROWS * N_COLS;

    f16* xq = (f16*)d_ws;
    f16* wq = (f16*)((char*)d_ws + (size_t)M_PAD * K_DIM * sizeof(f16));

    (void)hipFuncSetAttribute((const void*)gemm_kernel,
                              hipFuncAttributeMaxDynamicSharedMemorySize, 131072);

    {
        int threads = M_PAD * (K_DIM / 8);
        quant_x_kernel<<<threads / 256, 256, 0, stream>>>(x, xq);
    }
    {
        int threads = N_COLS * (K_DIM / 8);
        quant_w_kernel<<<threads / 256, 256, 0, stream>>>(weight, wq, scale_w);
    }
    {
        int grid = (M_PAD / 256) * (N_COLS / 256);   // 47 * 20 = 940
        gemm_kernel<<<grid, 512, 131072, stream>>>(xq, wq, bias, out);
    }
}